// Round 9
// baseline (442.197 us; speedup 1.0000x reference)
//
#include <hip/hip_runtime.h>
#include <hip/hip_bf16.h>
#include <math.h>
#include <stdint.h>

#define DDIM 512
#define QN   256
#define MT   128            // rows per block
#define WAVES 8
#define NT   512
#define KNN  5
#define BK   32
#define NSTEP (DDIM / BK)   // 16
#define BBUF 16384          // B tile per buffer: 16 frags x 1 KB (256 q x 32 k bf16)
#define ABUF 8192           // A tile per buffer:  8 frags x 1 KB (128 r x 32 k bf16)
#define BIGF 3.0e38f

typedef __attribute__((ext_vector_type(8))) short bf16x8;
typedef __attribute__((ext_vector_type(4))) float f32x4;

// async global->LDS: LDS dest = wave-uniform base + lane*16 (linear); the
// per-lane GLOBAL source address carries the fragment-order permutation.
__device__ __forceinline__ void gload16(const void* g, void* l) {
    __builtin_amdgcn_global_load_lds(
        (const __attribute__((address_space(1))) void*)g,
        (__attribute__((address_space(3))) void*)l, 16, 0, 0);
}

__device__ __forceinline__ bf16x8 pack8(float4 a, float4 b) {
    union { bf16x8 v; __hip_bfloat162 h[4]; } u;
    u.h[0] = __float22bfloat162_rn(make_float2(a.x, a.y));
    u.h[1] = __float22bfloat162_rn(make_float2(a.z, a.w));
    u.h[2] = __float22bfloat162_rn(make_float2(b.x, b.y));
    u.h[3] = __float22bfloat162_rn(make_float2(b.z, b.w));
    return u.v;
}
__device__ __forceinline__ float sq8(float4 a, float4 b, float s) {
    s = fmaf(a.x,a.x,s); s = fmaf(a.y,a.y,s); s = fmaf(a.z,a.z,s); s = fmaf(a.w,a.w,s);
    s = fmaf(b.x,b.x,s); s = fmaf(b.y,b.y,s); s = fmaf(b.z,b.z,s); s = fmaf(b.w,b.w,s);
    return s;
}

// Packed top-5 insert (idx in low 7 mantissa bits). Static indices only.
__device__ __forceinline__ void t5p_insert(float (&s)[KNN], float v) {
    if (v < s[4]) {
        s[4] = v;
        if (s[4] < s[3]) { float t = s[3]; s[3] = s[4]; s[4] = t; }
        if (s[3] < s[2]) { float t = s[2]; s[2] = s[3]; s[3] = t; }
        if (s[2] < s[1]) { float t = s[1]; s[1] = s[2]; s[2] = t; }
        if (s[1] < s[0]) { float t = s[0]; s[0] = s[1]; s[1] = t; }
    }
}
__device__ __forceinline__ void t5_insert(float (&s)[KNN], int (&ix)[KNN], float v, int vi) {
    if (v < s[4]) {
        s[4] = v; ix[4] = vi;
        if (s[4] < s[3]) { float t = s[3]; s[3] = s[4]; s[4] = t; int u = ix[3]; ix[3] = ix[4]; ix[4] = u; }
        if (s[3] < s[2]) { float t = s[2]; s[2] = s[3]; s[3] = t; int u = ix[2]; ix[2] = ix[3]; ix[3] = u; }
        if (s[2] < s[1]) { float t = s[1]; s[1] = s[2]; s[2] = t; int u = ix[1]; ix[1] = ix[2]; ix[2] = u; }
        if (s[1] < s[0]) { float t = s[0]; s[0] = s[1]; s[1] = t; int u = ix[0]; ix[0] = ix[1]; ix[1] = u; }
    }
}

// Phase 0: queries f32 -> bf16 (256 KB, L2-resident afterwards)
__global__ void conv_q(const float* __restrict__ emb, unsigned short* __restrict__ qbf) {
    int i = blockIdx.x * 256 + threadIdx.x;
    float4 v = ((const float4*)emb)[i];
    union { ushort4 u; __hip_bfloat162 h[2]; } o;
    o.h[0] = __float22bfloat162_rn(make_float2(v.x, v.y));
    o.h[1] = __float22bfloat162_rn(make_float2(v.z, v.w));
    ((ushort4*)qbf)[i] = o.u;
}

// Phase A: 128-row chunks; 8 waves in a 2x4 grid of 64x64 output tiles.
// Both operands live in fragment-order LDS (1 KB per 16x32 frag, read as
// base+lane*16, conflict-free). B staged by gload_lds (fragment-order global
// source); A staged once (each mem byte read ONCE), converted to bf16 by the
// stager which also accumulates ||m||^2. Double-buffered, 1 barrier/step.
__global__ __launch_bounds__(NT, 4) void knn_partial(
        const float* __restrict__ mem, const unsigned short* __restrict__ qbf,
        float* __restrict__ cand, int N) {
    __shared__ union {
        struct { char b[2][BBUF]; char a[2][ABUF]; } k;   // 48 KB (K-loop)
        float mbuf[2][QN][KNN];                           // 10 KB (epilogue)
    } sm;
    __shared__ float smsq[MT];

    const int tid  = threadIdx.x;
    const int lane = tid & 63;
    const int w    = tid >> 6;          // 0..7
    const int l15  = lane & 15;
    const int lq   = lane >> 4;         // k-slice 0..3
    const int rw   = w & 1;             // row-half: rows rw*64..+63
    const int qw   = w >> 1;            // q-quarter: q qw*64..+63
    const int chunk = blockIdx.x;
    const int rbase = chunk * MT;

    // ---- stager role (per wave w): A-frag w (rows w*16..+15) + B-units 2w,2w+1
    int srow = rbase + w * 16 + l15; if (srow >= N) srow = N - 1;
    const float* pA = mem + (size_t)srow * DDIM + lq * 8;       // + s*32 f32/step
    const char* qs0 = (const char*)qbf + (size_t)((2*w)   * 16 + l15) * 1024 + lq * 16;
    const char* qs1 = (const char*)qbf + (size_t)((2*w+1) * 16 + l15) * 1024 + lq * 16;

    f32x4 acc[4][4];
    const f32x4 z4 = {0.f, 0.f, 0.f, 0.f};
#pragma unroll
    for (int rf = 0; rf < 4; ++rf)
#pragma unroll
        for (int g = 0; g < 4; ++g) acc[rf][g] = z4;
    float sq = 0.f;

    // prologue: stage step 0 into buffer 0
    gload16(qs0, sm.k.b[0] + (2*w)   * 1024);
    gload16(qs1, sm.k.b[0] + (2*w+1) * 1024);
    {
        float4 f0 = *(const float4*)(pA);
        float4 f1 = *(const float4*)(pA + 4);
        bf16x8 a = pack8(f0, f1);
        sq = sq8(f0, f1, sq);
        *(bf16x8*)(sm.k.a[0] + w * 1024 + lane * 16) = a;
    }
    __syncthreads();

    for (int s = 0; s < NSTEP; ++s) {
        const int cur = s & 1, nxt = cur ^ 1;
        const bool pre = (s + 1 < NSTEP);
        float4 f0, f1;
        if (pre) {                       // issue next-step staging at TOP
            gload16(qs0 + (s + 1) * 64, sm.k.b[nxt] + (2*w)   * 1024);
            gload16(qs1 + (s + 1) * 64, sm.k.b[nxt] + (2*w+1) * 1024);
            f0 = *(const float4*)(pA + (s + 1) * BK);
            f1 = *(const float4*)(pA + (s + 1) * BK + 4);
        }
        // fragment reads: all linear base+lane*16 (conflict-free)
        bf16x8 ar[4], br[4];
#pragma unroll
        for (int rf = 0; rf < 4; ++rf)
            ar[rf] = *(const bf16x8*)(sm.k.a[cur] + (rw * 4 + rf) * 1024 + lane * 16);
#pragma unroll
        for (int g = 0; g < 4; ++g)
            br[g] = *(const bf16x8*)(sm.k.b[cur] + (qw * 4 + g) * 1024 + lane * 16);
#pragma unroll
        for (int rf = 0; rf < 4; ++rf)
#pragma unroll
            for (int g = 0; g < 4; ++g)
                acc[rf][g] = __builtin_amdgcn_mfma_f32_16x16x32_bf16(ar[rf], br[g], acc[rf][g], 0, 0, 0);
        if (pre) {                       // convert + write A(s+1), accumulate ||m||^2
            bf16x8 a = pack8(f0, f1);
            sq = sq8(f0, f1, sq);
            *(bf16x8*)(sm.k.a[nxt] + w * 1024 + lane * 16) = a;
        }
        __syncthreads();                 // one barrier per step (dbuf)
    }

    // ||m||^2 per row (stager rows w*16..+15; reduce k-slices across lq)
    sq += __shfl_xor(sq, 16);
    sq += __shfl_xor(sq, 32);
    if (lane < 16) smsq[w * 16 + lane] = sq;
    __syncthreads();
    float rsq[4][4];
#pragma unroll
    for (int rf = 0; rf < 4; ++rf)
        *(float4*)rsq[rf] = *(const float4*)&smsq[rw * 64 + rf * 16 + lq * 4];

    // epilogue: per q-frag g, scores over this wave's 64 rows -> lane top5 ->
    // shfl merge (lanes sharing l15) -> mbuf[rw] -> final cross-rw merge
#pragma unroll
    for (int g = 0; g < 4; ++g) {
        float ts[KNN] = {BIGF, BIGF, BIGF, BIGF, BIGF};
#pragma unroll
        for (int rf = 0; rf < 4; ++rf)
#pragma unroll
            for (int e = 0; e < 4; ++e) {
                int rl = rw * 64 + rf * 16 + lq * 4 + e;      // chunk-local row
                if (rbase + rl < N) {
                    float sc = fmaf(-2.f, acc[rf][g][e], rsq[rf][e]);
                    t5p_insert(ts, __int_as_float((__float_as_int(sc) & ~127) | rl));
                }
            }
#pragma unroll
        for (int x = 16; x <= 32; x <<= 1) {
            float os[KNN];
#pragma unroll
            for (int c = 0; c < KNN; ++c) os[c] = __shfl_xor(ts[c], x);
#pragma unroll
            for (int c = 0; c < KNN; ++c) t5p_insert(ts, os[c]);
        }
        if (lane < 16) {
            int q = qw * 64 + g * 16 + lane;
#pragma unroll
            for (int c = 0; c < KNN; ++c) sm.mbuf[rw][q][c] = ts[c];
        }
    }
    __syncthreads();
    if (tid < QN) {      // query tid: merge the 2 row-halves, coalesced write
        float fsv[KNN] = {BIGF, BIGF, BIGF, BIGF, BIGF};
#pragma unroll
        for (int c = 0; c < KNN; ++c) t5p_insert(fsv, sm.mbuf[0][tid][c]);
#pragma unroll
        for (int c = 0; c < KNN; ++c) t5p_insert(fsv, sm.mbuf[1][tid][c]);
        float* dst = cand + ((size_t)chunk * QN + tid) * KNN;
#pragma unroll
        for (int c = 0; c < KNN; ++c) dst[c] = fsv[c];
    }
}

// Phase B: one wave per query: global top-5 over NC*5 packed candidates,
// gather rows, exact f32 distances (immune to bf16/packing jitter), sum.
__global__ void knn_merge_exact(const float* __restrict__ emb, const float* __restrict__ mem,
                                const float* __restrict__ cand, float* __restrict__ qsum,
                                int Q, int NC) {
    const int q = blockIdx.x;
    const int lane = threadIdx.x;  // 64
    float fs[KNN] = {BIGF, BIGF, BIGF, BIGF, BIGF};
    int   fi[KNN] = {0, 0, 0, 0, 0};
    for (int c = lane; c < NC; c += 64) {
        const float* p = cand + ((size_t)c * Q + q) * KNN;
#pragma unroll
        for (int k = 0; k < KNN; ++k) {
            float pk = p[k];
            int idx = c * MT + (__float_as_int(pk) & 127);
            t5_insert(fs, fi, pk, idx);
        }
    }
    __shared__ float2 ls[64][KNN];
    __shared__ int sel[KNN];
#pragma unroll
    for (int k = 0; k < KNN; ++k) ls[lane][k] = make_float2(fs[k], __int_as_float(fi[k]));
    __syncthreads();
    if (lane == 0) {
        float gs[KNN] = {BIGF, BIGF, BIGF, BIGF, BIGF};
        int   gi[KNN] = {0, 0, 0, 0, 0};
        for (int l = 0; l < 64; ++l)
#pragma unroll
            for (int k = 0; k < KNN; ++k)
                t5_insert(gs, gi, ls[l][k].x, __float_as_int(ls[l][k].y));
#pragma unroll
        for (int k = 0; k < KNN; ++k) sel[k] = gi[k];
    }
    __syncthreads();
    const float4* qp = (const float4*)(emb + (size_t)q * DDIM);
    float4 q0 = qp[lane * 2], q1 = qp[lane * 2 + 1];
    float ssum = 0.f;
    for (int k = 0; k < KNN; ++k) {
        const float4* mp = (const float4*)(mem + (size_t)sel[k] * DDIM);
        float4 m0 = mp[lane * 2], m1 = mp[lane * 2 + 1];
        float d0 = m0.x - q0.x, d1 = m0.y - q0.y, d2 = m0.z - q0.z, d3 = m0.w - q0.w;
        float d4 = m1.x - q1.x, d5 = m1.y - q1.y, d6 = m1.z - q1.z, d7 = m1.w - q1.w;
        float t = d0*d0 + d1*d1 + d2*d2 + d3*d3 + d4*d4 + d5*d5 + d6*d6 + d7*d7;
#pragma unroll
        for (int off = 32; off > 0; off >>= 1) t += __shfl_down(t, off);
        if (lane == 0) ssum += sqrtf(t);
    }
    if (lane == 0) qsum[q] = ssum;
}

__global__ void knn_reduce(const float* __restrict__ qsum, float* __restrict__ out, int Q) {
    const int lane = threadIdx.x;
    float v = 0.f;
    for (int i = lane; i < Q; i += 64) v += qsum[i];
#pragma unroll
    for (int off = 32; off > 0; off >>= 1) v += __shfl_down(v, off);
    if (lane == 0) out[0] = v / (float)(Q * KNN);
}

extern "C" void kernel_launch(void* const* d_in, const int* in_sizes, int n_in,
                              void* d_out, int out_size, void* d_ws, size_t ws_size,
                              hipStream_t stream) {
    (void)n_in; (void)out_size; (void)ws_size;
    const float* emb = (const float*)d_in[0];
    const float* mem = (const float*)d_in[1];
    const int Q  = in_sizes[0] / DDIM;       // 256
    const int N  = in_sizes[1] / DDIM;       // 200000
    const int NC = (N + MT - 1) / MT;        // 1563

    float*          cand = (float*)d_ws;                                         // NC*Q*5*4B ~ 8 MB
    float*          qsum = (float*)((char*)d_ws + (size_t)NC * Q * KNN * 4);     // 1 KB
    unsigned short* qbf  = (unsigned short*)((char*)d_ws + (size_t)NC * Q * KNN * 4 + 1024);

    conv_q<<<(Q * DDIM / 4 + 255) / 256, 256, 0, stream>>>(emb, qbf);
    knn_partial<<<NC, NT, 0, stream>>>(mem, qbf, cand, N);
    knn_merge_exact<<<Q, 64, 0, stream>>>(emb, mem, cand, qsum, Q, NC);
    knn_reduce<<<1, 64, 0, stream>>>(qsum, (float*)d_out, Q);
}

// Round 10
// 210.879 us; speedup vs baseline: 2.0969x; 2.0969x over previous
//
#include <hip/hip_runtime.h>
#include <hip/hip_bf16.h>
#include <math.h>
#include <stdint.h>

#define DDIM 512
#define QN   256
#define MT   128            // rows per block
#define WAVES 8
#define NT   512
#define KNN  5
#define BK   32
#define NSTEP (DDIM / BK)   // 16
#define ABUF 8192           // A: 8 frags x 1 KB (128 r x 32 k bf16), lane-order
#define BBUF 16384          // B: 16 frags x 1 KB (256 q x 32 k bf16), lane-order
#define BIGF 3.0e38f

typedef __attribute__((ext_vector_type(8))) short bf16x8;
typedef __attribute__((ext_vector_type(4))) float f32x4;

#define SB0() __builtin_amdgcn_sched_barrier(0)

// async global->LDS: dest = wave-uniform base (HW adds lane*16); source is
// per-lane. qfrag is pre-permuted to lane order so source is contiguous 1KB.
__device__ __forceinline__ void gload16(const void* g, void* l) {
    __builtin_amdgcn_global_load_lds(
        (const __attribute__((address_space(1))) void*)g,
        (__attribute__((address_space(3))) void*)l, 16, 0, 0);
}

__device__ __forceinline__ bf16x8 pack8(float4 a, float4 b) {
    union { bf16x8 v; __hip_bfloat162 h[4]; } u;
    u.h[0] = __float22bfloat162_rn(make_float2(a.x, a.y));
    u.h[1] = __float22bfloat162_rn(make_float2(a.z, a.w));
    u.h[2] = __float22bfloat162_rn(make_float2(b.x, b.y));
    u.h[3] = __float22bfloat162_rn(make_float2(b.z, b.w));
    return u.v;
}
__device__ __forceinline__ float sq8(float4 a, float4 b, float s) {
    s = fmaf(a.x,a.x,s); s = fmaf(a.y,a.y,s); s = fmaf(a.z,a.z,s); s = fmaf(a.w,a.w,s);
    s = fmaf(b.x,b.x,s); s = fmaf(b.y,b.y,s); s = fmaf(b.z,b.z,s); s = fmaf(b.w,b.w,s);
    return s;
}

// Packed top-5 insert (idx in low 7 mantissa bits). Static indices only.
__device__ __forceinline__ void t5p_insert(float (&s)[KNN], float v) {
    if (v < s[4]) {
        s[4] = v;
        if (s[4] < s[3]) { float t = s[3]; s[3] = s[4]; s[4] = t; }
        if (s[3] < s[2]) { float t = s[2]; s[2] = s[3]; s[3] = t; }
        if (s[2] < s[1]) { float t = s[1]; s[1] = s[2]; s[2] = t; }
        if (s[1] < s[0]) { float t = s[0]; s[0] = s[1]; s[1] = t; }
    }
}
__device__ __forceinline__ void t5_insert(float (&s)[KNN], int (&ix)[KNN], float v, int vi) {
    if (v < s[4]) {
        s[4] = v; ix[4] = vi;
        if (s[4] < s[3]) { float t = s[3]; s[3] = s[4]; s[4] = t; int u = ix[3]; ix[3] = ix[4]; ix[4] = u; }
        if (s[3] < s[2]) { float t = s[2]; s[2] = s[3]; s[3] = t; int u = ix[2]; ix[2] = ix[3]; ix[3] = u; }
        if (s[2] < s[1]) { float t = s[1]; s[1] = s[2]; s[2] = t; int u = ix[1]; ix[1] = ix[2]; ix[2] = u; }
        if (s[1] < s[0]) { float t = s[0]; s[0] = s[1]; s[1] = t; int u = ix[0]; ix[0] = ix[1]; ix[1] = u; }
    }
}

// Phase 0: queries f32 -> bf16 in LANE-ORDER fragment layout:
// qfrag[qb][ks][lane]*16B, lane = lq*16 + l15  <->  (q = qb*16+l15, k = ks*32+lq*8)
__global__ void conv_q(const float* __restrict__ emb, unsigned short* __restrict__ qfrag) {
    int t = blockIdx.x * 256 + threadIdx.x;     // 16384 threads: [qb][ks][lane]
    int l   = t & 63;
    int ks  = (t >> 6) & 15;
    int qb  = t >> 10;
    int q   = qb * 16 + (l & 15);
    int k   = ks * 32 + (l >> 4) * 8;
    const float* p = emb + (size_t)q * DDIM + k;
    float4 f0 = *(const float4*)(p);
    float4 f1 = *(const float4*)(p + 4);
    *(bf16x8*)(qfrag + (size_t)t * 8) = pack8(f0, f1);
}

// Phase A: 128-row chunks; 8 waves = 2 rw x 4 qw grid of 64x64 output tiles.
// A & B in lane-order LDS frags (all ds ops contiguous per wave -> conflict-
// free). A: stager wave converts its 16 rows (read ONCE from HBM) per step.
// B: gload_lds from pre-permuted qfrag, flying across barriers (counted vmcnt).
__global__ __launch_bounds__(NT, 4) void knn_partial(
        const float* __restrict__ mem, const unsigned short* __restrict__ qfrag,
        float* __restrict__ cand, int N) {
    __shared__ union {
        struct { char a[2][ABUF]; char b[2][BBUF]; } k;   // 48 KB (K-loop)
        float mbuf[2][QN][KNN];                           // 10 KB (epilogue)
    } sm;
    __shared__ float smsq[MT];

    const int tid  = threadIdx.x;
    const int lane = tid & 63;
    const int w    = tid >> 6;          // 0..7
    const int l15  = lane & 15;
    const int lq   = lane >> 4;
    const int rw   = w & 1;             // row-half (rows rw*64..+63)
    const int qw   = w >> 1;            // q-quarter (q qw*64..+63)
    const int chunk = blockIdx.x;
    const int rbase = chunk * MT;

    // stager: wave w owns rows w*16..+15 (each mem byte read once per dispatch)
    int srow = rbase + w * 16 + l15; if (srow >= N) srow = N - 1;
    const float* pA = mem + (size_t)srow * DDIM + lq * 8;
    // B staging: wave w stages frags 2w, 2w+1; source contiguous 1 KB per gload
    const char* qsB0 = (const char*)qfrag + (size_t)(2 * w)     * 16384 + lane * 16;
    const char* qsB1 = (const char*)qfrag + (size_t)(2 * w + 1) * 16384 + lane * 16;

    f32x4 acc[4][4];
    const f32x4 z4 = {0.f, 0.f, 0.f, 0.f};
#pragma unroll
    for (int rf = 0; rf < 4; ++rf)
#pragma unroll
        for (int g = 0; g < 4; ++g) acc[rf][g] = z4;
    float sq = 0.f;

    // prologue: stage step 0
    gload16(qsB0, sm.k.b[0] + (2 * w) * 1024);
    gload16(qsB1, sm.k.b[0] + (2 * w + 1) * 1024);
    {
        float4 f0 = *(const float4*)(pA);
        float4 f1 = *(const float4*)(pA + 4);
        sq = sq8(f0, f1, sq);
        *(bf16x8*)(sm.k.a[0] + w * 1024 + lane * 16) = pack8(f0, f1);
    }
    asm volatile("s_waitcnt lgkmcnt(0) vmcnt(0)" ::: "memory");
    __builtin_amdgcn_s_barrier();
    SB0();

    for (int s = 0; s < NSTEP; ++s) {
        const int cur = s & 1, nxt = cur ^ 1;
        const bool pre = (s + 1 < NSTEP);
        // land B(cur) gloads (issued late last step; ~free by now)
        asm volatile("s_waitcnt vmcnt(0)" ::: "memory");
        SB0();
        float4 f0, f1;
        if (pre) {                      // A f32 prefetch: full-step window
            f0 = *(const float4*)(pA + (s + 1) * BK);
            f1 = *(const float4*)(pA + (s + 1) * BK + 4);
        }
        SB0();
        const char* ab = sm.k.a[cur];
        const char* bb = sm.k.b[cur];
        bf16x8 ar0 = *(const bf16x8*)(ab + (rw * 4 + 0) * 1024 + lane * 16);
        bf16x8 ar1 = *(const bf16x8*)(ab + (rw * 4 + 1) * 1024 + lane * 16);
        bf16x8 ar2 = *(const bf16x8*)(ab + (rw * 4 + 2) * 1024 + lane * 16);
        bf16x8 ar3 = *(const bf16x8*)(ab + (rw * 4 + 3) * 1024 + lane * 16);
#pragma unroll
        for (int g = 0; g < 4; ++g) {   // br streamed: one frag live at a time
            bf16x8 br = *(const bf16x8*)(bb + (qw * 4 + g) * 1024 + lane * 16);
            acc[0][g] = __builtin_amdgcn_mfma_f32_16x16x32_bf16(ar0, br, acc[0][g], 0, 0, 0);
            acc[1][g] = __builtin_amdgcn_mfma_f32_16x16x32_bf16(ar1, br, acc[1][g], 0, 0, 0);
            acc[2][g] = __builtin_amdgcn_mfma_f32_16x16x32_bf16(ar2, br, acc[2][g], 0, 0, 0);
            acc[3][g] = __builtin_amdgcn_mfma_f32_16x16x32_bf16(ar3, br, acc[3][g], 0, 0, 0);
        }
        SB0();
        if (pre) {
            // B(s+1) gloads issued now -> fly across the barrier
            gload16(qsB0 + (s + 1) * 1024, sm.k.b[nxt] + (2 * w) * 1024);
            gload16(qsB1 + (s + 1) * 1024, sm.k.b[nxt] + (2 * w + 1) * 1024);
            sq = sq8(f0, f1, sq);       // pack waits f0/f1 (older than gloads)
            *(bf16x8*)(sm.k.a[nxt] + w * 1024 + lane * 16) = pack8(f0, f1);
        }
        SB0();
        asm volatile("s_waitcnt lgkmcnt(0)" ::: "memory");  // my ds reads+write done
        __builtin_amdgcn_s_barrier();                       // vmcnt NOT drained
        SB0();
    }

    // ||m||^2 per row (stager rows w*16..+15; reduce k-slices across lq)
    sq += __shfl_xor(sq, 16);
    sq += __shfl_xor(sq, 32);
    if (lane < 16) smsq[w * 16 + lane] = sq;
    __syncthreads();
    float rsq[4][4];
#pragma unroll
    for (int rf = 0; rf < 4; ++rf)
        *(float4*)rsq[rf] = *(const float4*)&smsq[rw * 64 + rf * 16 + lq * 4];

    // epilogue: 4 q-groups per wave -> lane top5 -> shfl merge -> mbuf
#pragma unroll
    for (int g = 0; g < 4; ++g) {
        float ts[KNN] = {BIGF, BIGF, BIGF, BIGF, BIGF};
#pragma unroll
        for (int rf = 0; rf < 4; ++rf)
#pragma unroll
            for (int e = 0; e < 4; ++e) {
                int rl = rw * 64 + rf * 16 + lq * 4 + e;      // chunk-local row
                if (rbase + rl < N) {
                    float sc = fmaf(-2.f, acc[rf][g][e], rsq[rf][e]);
                    t5p_insert(ts, __int_as_float((__float_as_int(sc) & ~127) | rl));
                }
            }
#pragma unroll
        for (int x = 16; x <= 32; x <<= 1) {
            float os[KNN];
#pragma unroll
            for (int c = 0; c < KNN; ++c) os[c] = __shfl_xor(ts[c], x);
#pragma unroll
            for (int c = 0; c < KNN; ++c) t5p_insert(ts, os[c]);
        }
        if (lane < 16) {
            int q = qw * 64 + g * 16 + lane;
#pragma unroll
            for (int c = 0; c < KNN; ++c) sm.mbuf[rw][q][c] = ts[c];
        }
    }
    __syncthreads();
    if (tid < QN) {      // query tid: merge the 2 row-halves, coalesced write
        float fsv[KNN] = {BIGF, BIGF, BIGF, BIGF, BIGF};
#pragma unroll
        for (int c = 0; c < KNN; ++c) t5p_insert(fsv, sm.mbuf[0][tid][c]);
#pragma unroll
        for (int c = 0; c < KNN; ++c) t5p_insert(fsv, sm.mbuf[1][tid][c]);
        float* dst = cand + ((size_t)chunk * QN + tid) * KNN;
#pragma unroll
        for (int c = 0; c < KNN; ++c) dst[c] = fsv[c];
    }
}

// Phase B: one wave per query: global top-5 over NC*5 packed candidates,
// gather rows, exact f32 distances (immune to bf16/packing jitter), sum.
__global__ void knn_merge_exact(const float* __restrict__ emb, const float* __restrict__ mem,
                                const float* __restrict__ cand, float* __restrict__ qsum,
                                int Q, int NC) {
    const int q = blockIdx.x;
    const int lane = threadIdx.x;  // 64
    float fs[KNN] = {BIGF, BIGF, BIGF, BIGF, BIGF};
    int   fi[KNN] = {0, 0, 0, 0, 0};
    for (int c = lane; c < NC; c += 64) {
        const float* p = cand + ((size_t)c * Q + q) * KNN;
#pragma unroll
        for (int k = 0; k < KNN; ++k) {
            float pk = p[k];
            int idx = c * MT + (__float_as_int(pk) & 127);
            t5_insert(fs, fi, pk, idx);
        }
    }
    __shared__ float2 ls[64][KNN];
    __shared__ int sel[KNN];
#pragma unroll
    for (int k = 0; k < KNN; ++k) ls[lane][k] = make_float2(fs[k], __int_as_float(fi[k]));
    __syncthreads();
    if (lane == 0) {
        float gs[KNN] = {BIGF, BIGF, BIGF, BIGF, BIGF};
        int   gi[KNN] = {0, 0, 0, 0, 0};
        for (int l = 0; l < 64; ++l)
#pragma unroll
            for (int k = 0; k < KNN; ++k)
                t5_insert(gs, gi, ls[l][k].x, __float_as_int(ls[l][k].y));
#pragma unroll
        for (int k = 0; k < KNN; ++k) sel[k] = gi[k];
    }
    __syncthreads();
    const float4* qp = (const float4*)(emb + (size_t)q * DDIM);
    float4 q0 = qp[lane * 2], q1 = qp[lane * 2 + 1];
    float ssum = 0.f;
    for (int k = 0; k < KNN; ++k) {
        const float4* mp = (const float4*)(mem + (size_t)sel[k] * DDIM);
        float4 m0 = mp[lane * 2], m1 = mp[lane * 2 + 1];
        float d0 = m0.x - q0.x, d1 = m0.y - q0.y, d2 = m0.z - q0.z, d3 = m0.w - q0.w;
        float d4 = m1.x - q1.x, d5 = m1.y - q1.y, d6 = m1.z - q1.z, d7 = m1.w - q1.w;
        float t = d0*d0 + d1*d1 + d2*d2 + d3*d3 + d4*d4 + d5*d5 + d6*d6 + d7*d7;
#pragma unroll
        for (int off = 32; off > 0; off >>= 1) t += __shfl_down(t, off);
        if (lane == 0) ssum += sqrtf(t);
    }
    if (lane == 0) qsum[q] = ssum;
}

__global__ void knn_reduce(const float* __restrict__ qsum, float* __restrict__ out, int Q) {
    const int lane = threadIdx.x;
    float v = 0.f;
    for (int i = lane; i < Q; i += 64) v += qsum[i];
#pragma unroll
    for (int off = 32; off > 0; off >>= 1) v += __shfl_down(v, off);
    if (lane == 0) out[0] = v / (float)(Q * KNN);
}

extern "C" void kernel_launch(void* const* d_in, const int* in_sizes, int n_in,
                              void* d_out, int out_size, void* d_ws, size_t ws_size,
                              hipStream_t stream) {
    (void)n_in; (void)out_size; (void)ws_size;
    const float* emb = (const float*)d_in[0];
    const float* mem = (const float*)d_in[1];
    const int Q  = in_sizes[0] / DDIM;       // 256
    const int N  = in_sizes[1] / DDIM;       // 200000
    const int NC = (N + MT - 1) / MT;        // 1563

    float*          cand  = (float*)d_ws;                                        // NC*Q*5*4B ~ 8 MB
    float*          qsum  = (float*)((char*)d_ws + (size_t)NC * Q * KNN * 4);    // 1 KB
    unsigned short* qfrag = (unsigned short*)((char*)d_ws + (size_t)NC * Q * KNN * 4 + 1024);

    conv_q<<<64, 256, 0, stream>>>(emb, qfrag);
    knn_partial<<<NC, NT, 0, stream>>>(mem, qfrag, cand, N);
    knn_merge_exact<<<Q, 64, 0, stream>>>(emb, mem, cand, qsum, Q, NC);
    knn_reduce<<<1, 64, 0, stream>>>(qsum, (float*)d_out, Q);
}